// Round 6
// baseline (166.010 us; speedup 1.0000x reference)
//
#include <hip/hip_runtime.h>
#include <hip/hip_bf16.h>
#include <cstdint>

#define B_ 32
#define D_ 256
#define K_ 1024
#define N_TOK 32768
#define Z_ELEMS 8388608
#define OUT_IDX_OFF Z_ELEMS
#define OUT_LOSS_OFF (Z_ELEMS + N_TOK)

// ws layout:
//   [0,4096)             f32 cnorm[1024]
//   [4096,8192)          f32 partials[1024]
//   [8192,532480)        cb_frag bf16, fragment-order: g=((cblk*8+kc)*8+ct)*64+lane, 16B per g
//   [532480,2629632)     u32 top2[8 cblk][32768 tok][2]
#define WS_CNORM_OFF 0
#define WS_PART_OFF  4096
#define WS_CBF_OFF   8192
#define WS_TOP2_OFF  532480

#define MARGIN 1.25f

typedef __attribute__((ext_vector_type(8))) short short8v;
typedef __attribute__((ext_vector_type(4))) float f32x4;
typedef unsigned long long u64;

__device__ __forceinline__ unsigned short f2bf(float x) {
    unsigned u = __float_as_uint(x);
    return (unsigned short)((u + 0x7fffu + ((u >> 16) & 1u)) >> 16);  // RNE
}
__device__ __forceinline__ unsigned packf(float f) {
    unsigned u = __float_as_uint(f);
    return (u & 0x80000000u) ? ~u : (u | 0x80000000u);  // order-preserving bits
}
__device__ __forceinline__ float unpackf(unsigned p) {
    unsigned u = (p & 0x80000000u) ? (p & 0x7fffffffu) : ~p;
    return __uint_as_float(u);
}

// ---------------- kernel 0: cnorm (fp32) + cb -> bf16 fragment order ----------------
__global__ __launch_bounds__(256)
void prep_kernel(const float* __restrict__ cb, float* __restrict__ cnorm,
                 unsigned char* __restrict__ cbf) {
    const int t = threadIdx.x;
    const int blk = blockIdx.x;  // 16 blocks
    {   // cnorm: 64 codes per block, 4 threads each
        int k = blk * 64 + (t >> 2);
        int part = t & 3;
        const float4* row = reinterpret_cast<const float4*>(cb + k * D_);
        float s = 0.f;
#pragma unroll
        for (int j = 0; j < 16; ++j) {
            float4 v = row[part * 16 + j];
            s += v.x * v.x + v.y * v.y + v.z * v.z + v.w * v.w;
        }
        s += __shfl_xor(s, 1);
        s += __shfl_xor(s, 2);
        if (part == 0) cnorm[k] = s;
    }
    // fragment reorder: unit g -> (cblk,kc,ct,lane); 8 units per thread
#pragma unroll
    for (int w = 0; w < 8; ++w) {
        int g = blk * 2048 + w * 256 + t;
        int lane = g & 63, ct = (g >> 6) & 7, kc = (g >> 9) & 7, cblk = g >> 12;
        int code = cblk * 128 + ct * 16 + (lane & 15);
        int d0 = kc * 32 + (lane >> 4) * 8;
        const float* src = cb + code * 256 + d0;
        float4 a = *reinterpret_cast<const float4*>(src);
        float4 b2 = *reinterpret_cast<const float4*>(src + 4);
        uint4 pk;
        pk.x = (unsigned)f2bf(a.x) | ((unsigned)f2bf(a.y) << 16);
        pk.y = (unsigned)f2bf(a.z) | ((unsigned)f2bf(a.w) << 16);
        pk.z = (unsigned)f2bf(b2.x) | ((unsigned)f2bf(b2.y) << 16);
        pk.w = (unsigned)f2bf(b2.z) | ((unsigned)f2bf(b2.w) << 16);
        *reinterpret_cast<uint4*>(cbf + (size_t)g * 16) = pk;
    }
}

// ---------------- kernel 1: bf16 MFMA screen, 8 waves/block for 4 waves/SIMD ----------------
// 512 blocks x 512 thr (8 waves). Block = 64 tokens x 1024 codes.
// Wave wv owns cblk wv: 64 tok x 128 codes, two 64-code phases, running top-2.
__global__ __launch_bounds__(512, 4)
void screen_kernel(const float* __restrict__ z, const unsigned char* __restrict__ cbf,
                   const float* __restrict__ cnorm, unsigned* __restrict__ top2) {
    __shared__ __align__(16) unsigned char zfB[32768];  // [kc 8][ntg 4][lane 64][16B]
    __shared__ float cns[1024];

    const int t = threadIdx.x;
    const int lane = t & 63;
    const int wv = t >> 6;          // 0..7 = this wave's cblk
    const int blk = blockIdx.x;
    const int b = blk >> 4;
    const int hw0 = (blk & 15) << 6;
    const float* zb = z + ((size_t)b << 18) + hw0;

    for (int i = t; i < 1024; i += 512) cns[i] = cnorm[i];

    {   // stage 64 tok x 256 d -> bf16 B-fragments (once per block; 32 d per thread)
        const int tok = t & 63;
        const int kc = t >> 6;      // 0..7: 32-d block
#pragma unroll
        for (int u = 0; u < 4; ++u) {
            int d0 = kc * 32 + u * 8;
            float v[8];
#pragma unroll
            for (int j = 0; j < 8; ++j) v[j] = zb[(size_t)(d0 + j) * 1024 + tok];
            uint4 pk;
            pk.x = (unsigned)f2bf(v[0]) | ((unsigned)f2bf(v[1]) << 16);
            pk.y = (unsigned)f2bf(v[2]) | ((unsigned)f2bf(v[3]) << 16);
            pk.z = (unsigned)f2bf(v[4]) | ((unsigned)f2bf(v[5]) << 16);
            pk.w = (unsigned)f2bf(v[6]) | ((unsigned)f2bf(v[7]) << 16);
            int slot = (kc * 4 + (tok >> 4)) * 64 + u * 16 + (tok & 15);
            *reinterpret_cast<uint4*>(zfB + slot * 16) = pk;
        }
    }
    __syncthreads();

    const int rbase = (lane >> 4) << 2;
    const unsigned char* abase = cbf + (size_t)wv * 65536 + lane * 16;
    const unsigned char* zrd = zfB + lane * 16;

    unsigned k1[4], k2[4];
#pragma unroll
    for (int nt = 0; nt < 4; ++nt) { k1[nt] = 0xFFFFFFFFu; k2[nt] = 0xFFFFFFFFu; }

#pragma unroll
    for (int p = 0; p < 2; ++p) {
        f32x4 acc[4][4];
#pragma unroll
        for (int mt = 0; mt < 4; ++mt)
#pragma unroll
            for (int nt = 0; nt < 4; ++nt) acc[mt][nt] = (f32x4){0.f, 0.f, 0.f, 0.f};

#pragma unroll
        for (int kc = 0; kc < 8; ++kc) {
            short8v bfv[4];
#pragma unroll
            for (int nt = 0; nt < 4; ++nt)
                bfv[nt] = *reinterpret_cast<const short8v*>(zrd + (kc * 4 + nt) * 1024);
#pragma unroll
            for (int mt = 0; mt < 4; ++mt) {
                short8v af = *reinterpret_cast<const short8v*>(
                    abase + (kc * 8 + p * 4 + mt) * 1024);
#pragma unroll
                for (int nt = 0; nt < 4; ++nt)
                    acc[mt][nt] = __builtin_amdgcn_mfma_f32_16x16x32_bf16(
                        af, bfv[nt], acc[mt][nt], 0, 0, 0);
            }
        }

        // fold this phase's 64 codes into the running per-token top-2
#pragma unroll
        for (int nt = 0; nt < 4; ++nt) {
#pragma unroll
            for (int mt = 0; mt < 4; ++mt) {
#pragma unroll
                for (int r = 0; r < 4; ++r) {
                    int code = wv * 128 + (p * 4 + mt) * 16 + rbase + r;
                    float d2a = fmaf(-2.0f, acc[mt][nt][r], cns[code]);
                    unsigned key = (packf(d2a) & 0xFFFFFC00u) | (unsigned)code;
                    if (key < k1[nt]) { k2[nt] = k1[nt]; k1[nt] = key; }
                    else if (key < k2[nt]) { k2[nt] = key; }
                }
            }
        }
    }

    // reduce across the 4 row-groups and write per-cblk top-2
#pragma unroll
    for (int nt = 0; nt < 4; ++nt) {
        unsigned a1 = k1[nt], a2 = k2[nt];
#pragma unroll
        for (int x = 16; x <= 32; x <<= 1) {
            unsigned o1 = __shfl_xor(a1, x);
            unsigned o2 = __shfl_xor(a2, x);
            unsigned n1, n2;
            if (a1 < o1) { n1 = a1; n2 = (a2 < o1) ? a2 : o1; }
            else         { n1 = o1; n2 = (o2 < a1) ? o2 : a1; }
            a1 = n1; a2 = n2;
        }
        if (lane < 16) {
            int token = blk * 64 + nt * 16 + lane;
            *reinterpret_cast<uint2*>(top2 + ((size_t)wv * N_TOK + token) * 2) =
                make_uint2(a1, a2);
        }
    }
}

// ---------------- kernel 2: fused exact refine + gather + loss partials ----------------
__global__ __launch_bounds__(256)
void refgather_kernel(const float* __restrict__ z, const float* __restrict__ cb,
                      const float* __restrict__ cnorm, const unsigned* __restrict__ top2,
                      float* __restrict__ out, float* __restrict__ partials) {
    __shared__ float zsm[32][261];
    __shared__ float crows[32][257];
    __shared__ int cand[32][16];
    __shared__ int cnt[32];
    __shared__ u64 bestk[32];
    __shared__ int sidx[32];
    __shared__ float red[256];
    __shared__ int maxc;

    const int t = threadIdx.x;
    const int bh = blockIdx.x;  // 0..1023
    const int b = bh >> 5, h = bh & 31;
    const int n0 = b * 1024 + h * 32;
    const int w = t & 31, dg = t >> 5;

    {   // stage z rows (coalesced 128B segments)
        const float* zp = z + ((size_t)b << 18) + h * 32 + w;
#pragma unroll
        for (int i = 0; i < 32; ++i) {
            int d = dg * 32 + i;
            zsm[w][d] = zp[(size_t)d * 1024];
        }
    }
    if (t < 32) cnt[t] = 0;
    if (t == 0) maxc = 0;
    __syncthreads();

    const int tk = t >> 3, l8 = t & 7;
    {   // candidate collection from per-cblk top-2
        uint2 kk = *reinterpret_cast<const uint2*>(
            top2 + ((size_t)l8 * N_TOK + (n0 + tk)) * 2);
        unsigned mn = kk.x;  // k1 <= k2
#pragma unroll
        for (int x = 1; x < 8; x <<= 1) {
            unsigned o = __shfl_xor(mn, x);
            if (o < mn) mn = o;
        }
        float thr = unpackf(mn & 0xFFFFFC00u) + MARGIN;
        float da = unpackf(kk.x & 0xFFFFFC00u);
        if (da <= thr) { int p = atomicAdd(&cnt[tk], 1); cand[tk][p] = (int)(kk.x & 1023u); }
        float db = unpackf(kk.y & 0xFFFFFC00u);
        if (db <= thr) { int p = atomicAdd(&cnt[tk], 1); cand[tk][p] = (int)(kk.y & 1023u); }
    }
    __syncthreads();
    if (t < 32) atomicMax(&maxc, cnt[t]);
    __syncthreads();

    const int mc = maxc;
    u64 best = ~0ull;
    for (int ci = 0; ci < mc; ++ci) {
        if (ci < cnt[tk]) {
            int k = cand[tk][ci];
            const float* crow = cb + (size_t)k * 256;
            float s = 0.f;
#pragma unroll
            for (int j = 0; j < 32; ++j) {
                int d = j * 8 + l8;
                s = fmaf(zsm[tk][d], crow[d], s);
            }
#pragma unroll
            for (int x = 1; x < 8; x <<= 1) s += __shfl_xor(s, x);
            float d2 = cnorm[k] - 2.f * s;
            u64 key = ((u64)packf(d2) << 32) | (unsigned)k;
            if (key < best) best = key;
        }
    }
    if (l8 == 0) bestk[tk] = best;
    __syncthreads();
    if (t < 32) {
        int k = (int)(bestk[t] & 1023ull);
        sidx[t] = k;
        out[OUT_IDX_OFF + n0 + t] = (float)k;
    }
    __syncthreads();
    {   // stage chosen codebook rows (fp32)
        const int r = t & 31, q = t >> 5;
        const float4* src = reinterpret_cast<const float4*>(cb + (size_t)sidx[r] * 256 + q * 32);
#pragma unroll
        for (int j = 0; j < 8; ++j) {
            float4 v = src[j];
            int d = q * 32 + j * 4;
            crows[r][d] = v.x; crows[r][d + 1] = v.y;
            crows[r][d + 2] = v.z; crows[r][d + 3] = v.w;
        }
    }
    __syncthreads();
    float accl = 0.f;
    float* orow = out + ((size_t)b << 18) + h * 32 + w;
#pragma unroll
    for (int i = 0; i < 32; ++i) {
        const int d = dg * 32 + i;
        const float cv = crows[w][d];
        const float zv = zsm[w][d];
        orow[(size_t)d * 1024] = cv;
        const float df = cv - zv;
        accl += df * df;
    }
    red[t] = accl;
    __syncthreads();
    for (int s = 128; s > 0; s >>= 1) {
        if (t < s) red[t] += red[t + s];
        __syncthreads();
    }
    if (t == 0) partials[bh] = red[0];
}

// ---------------- kernel 3: deterministic final loss reduction ----------------
__global__ __launch_bounds__(256) void loss_kernel(const float* __restrict__ partials,
                                                   float* __restrict__ out) {
    __shared__ float red[256];
    const int t = threadIdx.x;
    float s = partials[t] + partials[t + 256] + partials[t + 512] + partials[t + 768];
    red[t] = s;
    __syncthreads();
    for (int st = 128; st > 0; st >>= 1) {
        if (t < st) red[t] += red[t + st];
        __syncthreads();
    }
    if (t == 0) out[OUT_LOSS_OFF] = red[0] * (1.25f / (float)Z_ELEMS);
}

extern "C" void kernel_launch(void* const* d_in, const int* in_sizes, int n_in,
                              void* d_out, int out_size, void* d_ws, size_t ws_size,
                              hipStream_t stream) {
    const float* z = (const float*)d_in[0];   // [32,256,32,32] f32
    const float* cb = (const float*)d_in[1];  // [1024,256] f32
    float* out = (float*)d_out;
    float* cnorm = (float*)((char*)d_ws + WS_CNORM_OFF);
    float* partials = (float*)((char*)d_ws + WS_PART_OFF);
    unsigned char* cbf = (unsigned char*)d_ws + WS_CBF_OFF;
    unsigned* top2 = (unsigned*)((char*)d_ws + WS_TOP2_OFF);

    prep_kernel<<<16, 256, 0, stream>>>(cb, cnorm, cbf);
    screen_kernel<<<512, 512, 0, stream>>>(z, cbf, cnorm, top2);
    refgather_kernel<<<1024, 256, 0, stream>>>(z, cb, cnorm, top2, out, partials);
    loss_kernel<<<1, 256, 0, stream>>>(partials, out);
}

// Round 7
// 104.744 us; speedup vs baseline: 1.5849x; 1.5849x over previous
//
#include <hip/hip_runtime.h>
#include <hip/hip_bf16.h>
#include <cstdint>

#define B_ 32
#define D_ 256
#define K_ 1024
#define N_TOK 32768
#define Z_ELEMS 8388608
#define OUT_IDX_OFF Z_ELEMS
#define OUT_LOSS_OFF (Z_ELEMS + N_TOK)

// ws layout:
//   [0,4096)             f32 cnorm[1024]
//   [4096,8192)          f32 partials[1024]
//   [8192,532480)        cb_frag bf16, fragment-order: g=((cblk*8+kc)*8+ct)*64+lane, 16B per g
//   [532480,2629632)     u32 top2[8 cblk][32768 tok][2]
#define WS_CNORM_OFF 0
#define WS_PART_OFF  4096
#define WS_CBF_OFF   8192
#define WS_TOP2_OFF  532480

#define MARGIN 1.25f

typedef __attribute__((ext_vector_type(8))) short short8v;
typedef __attribute__((ext_vector_type(4))) float f32x4;
typedef unsigned long long u64;

__device__ __forceinline__ unsigned short f2bf(float x) {
    unsigned u = __float_as_uint(x);
    return (unsigned short)((u + 0x7fffu + ((u >> 16) & 1u)) >> 16);  // RNE
}
__device__ __forceinline__ unsigned packf(float f) {
    unsigned u = __float_as_uint(f);
    return (u & 0x80000000u) ? ~u : (u | 0x80000000u);  // order-preserving bits
}
__device__ __forceinline__ float unpackf(unsigned p) {
    unsigned u = (p & 0x80000000u) ? (p & 0x7fffffffu) : ~p;
    return __uint_as_float(u);
}

// ---------------- kernel 0: cnorm (fp32) + cb -> bf16 fragment order ----------------
__global__ __launch_bounds__(256)
void prep_kernel(const float* __restrict__ cb, float* __restrict__ cnorm,
                 unsigned char* __restrict__ cbf) {
    const int t = threadIdx.x;
    const int blk = blockIdx.x;  // 16 blocks
    {   // cnorm: 64 codes per block, 4 threads each
        int k = blk * 64 + (t >> 2);
        int part = t & 3;
        const float4* row = reinterpret_cast<const float4*>(cb + k * D_);
        float s = 0.f;
#pragma unroll
        for (int j = 0; j < 16; ++j) {
            float4 v = row[part * 16 + j];
            s += v.x * v.x + v.y * v.y + v.z * v.z + v.w * v.w;
        }
        s += __shfl_xor(s, 1);
        s += __shfl_xor(s, 2);
        if (part == 0) cnorm[k] = s;
    }
    // fragment reorder: unit g -> (cblk,kc,ct,lane); 8 units per thread
#pragma unroll
    for (int w = 0; w < 8; ++w) {
        int g = blk * 2048 + w * 256 + t;
        int lane = g & 63, ct = (g >> 6) & 7, kc = (g >> 9) & 7, cblk = g >> 12;
        int code = cblk * 128 + ct * 16 + (lane & 15);
        int d0 = kc * 32 + (lane >> 4) * 8;
        const float* src = cb + code * 256 + d0;
        float4 a = *reinterpret_cast<const float4*>(src);
        float4 b2 = *reinterpret_cast<const float4*>(src + 4);
        uint4 pk;
        pk.x = (unsigned)f2bf(a.x) | ((unsigned)f2bf(a.y) << 16);
        pk.y = (unsigned)f2bf(a.z) | ((unsigned)f2bf(a.w) << 16);
        pk.z = (unsigned)f2bf(b2.x) | ((unsigned)f2bf(b2.y) << 16);
        pk.w = (unsigned)f2bf(b2.z) | ((unsigned)f2bf(b2.w) << 16);
        *reinterpret_cast<uint4*>(cbf + (size_t)g * 16) = pk;
    }
}

// ---------------- kernel 1: bf16 MFMA screen, 8 waves/block, spill-free ----------------
// 512 blocks x 512 thr (8 waves), 4 waves/SIMD. Block = 64 tokens x 1024 codes.
// Wave wv owns cblk wv: 64 tok x 128 codes as 4 phases x 32 codes (acc[2][4]=32 regs).
__global__ __launch_bounds__(512, 4)
void screen_kernel(const float* __restrict__ z, const unsigned char* __restrict__ cbf,
                   const float* __restrict__ cnorm, unsigned* __restrict__ top2) {
    __shared__ __align__(16) unsigned char zfB[32768];  // [kc 8][ntg 4][lane 64][16B]
    __shared__ float cns[1024];

    const int t = threadIdx.x;
    const int lane = t & 63;
    const int wv = t >> 6;          // 0..7 = this wave's cblk
    const int blk = blockIdx.x;
    const int b = blk >> 4;
    const int hw0 = (blk & 15) << 6;
    const float* zb = z + ((size_t)b << 18) + hw0;

    for (int i = t; i < 1024; i += 512) cns[i] = cnorm[i];

    {   // stage 64 tok x 256 d -> bf16 B-fragments (once per block; 32 d per thread)
        const int tok = t & 63;
        const int kc = t >> 6;      // 0..7: 32-d block
#pragma unroll
        for (int u = 0; u < 4; ++u) {
            int d0 = kc * 32 + u * 8;
            float v[8];
#pragma unroll
            for (int j = 0; j < 8; ++j) v[j] = zb[(size_t)(d0 + j) * 1024 + tok];
            uint4 pk;
            pk.x = (unsigned)f2bf(v[0]) | ((unsigned)f2bf(v[1]) << 16);
            pk.y = (unsigned)f2bf(v[2]) | ((unsigned)f2bf(v[3]) << 16);
            pk.z = (unsigned)f2bf(v[4]) | ((unsigned)f2bf(v[5]) << 16);
            pk.w = (unsigned)f2bf(v[6]) | ((unsigned)f2bf(v[7]) << 16);
            int slot = (kc * 4 + (tok >> 4)) * 64 + u * 16 + (tok & 15);
            *reinterpret_cast<uint4*>(zfB + slot * 16) = pk;
        }
    }
    __syncthreads();

    const int rbase = (lane >> 4) << 2;
    const unsigned char* abase = cbf + (size_t)wv * 65536 + lane * 16;
    const unsigned char* zrd = zfB + lane * 16;

    unsigned k1[4], k2[4];
#pragma unroll
    for (int nt = 0; nt < 4; ++nt) { k1[nt] = 0xFFFFFFFFu; k2[nt] = 0xFFFFFFFFu; }

    for (int p = 0; p < 4; ++p) {   // 4 phases x 32 codes
        f32x4 acc[2][4];
#pragma unroll
        for (int mt = 0; mt < 2; ++mt)
#pragma unroll
            for (int nt = 0; nt < 4; ++nt) acc[mt][nt] = (f32x4){0.f, 0.f, 0.f, 0.f};

#pragma unroll
        for (int kc = 0; kc < 8; ++kc) {
            short8v bfv[4];
#pragma unroll
            for (int nt = 0; nt < 4; ++nt)
                bfv[nt] = *reinterpret_cast<const short8v*>(zrd + (kc * 4 + nt) * 1024);
#pragma unroll
            for (int mt = 0; mt < 2; ++mt) {
                short8v af = *reinterpret_cast<const short8v*>(
                    abase + (kc * 8 + p * 2 + mt) * 1024);
#pragma unroll
                for (int nt = 0; nt < 4; ++nt)
                    acc[mt][nt] = __builtin_amdgcn_mfma_f32_16x16x32_bf16(
                        af, bfv[nt], acc[mt][nt], 0, 0, 0);
            }
        }

        // fold this phase's 32 codes into the running per-token top-2
#pragma unroll
        for (int nt = 0; nt < 4; ++nt) {
#pragma unroll
            for (int mt = 0; mt < 2; ++mt) {
#pragma unroll
                for (int r = 0; r < 4; ++r) {
                    int code = wv * 128 + (p * 2 + mt) * 16 + rbase + r;
                    float d2a = fmaf(-2.0f, acc[mt][nt][r], cns[code]);
                    unsigned key = (packf(d2a) & 0xFFFFFC00u) | (unsigned)code;
                    if (key < k1[nt]) { k2[nt] = k1[nt]; k1[nt] = key; }
                    else if (key < k2[nt]) { k2[nt] = key; }
                }
            }
        }
    }

    // reduce across the 4 row-groups and write per-cblk top-2
#pragma unroll
    for (int nt = 0; nt < 4; ++nt) {
        unsigned a1 = k1[nt], a2 = k2[nt];
#pragma unroll
        for (int x = 16; x <= 32; x <<= 1) {
            unsigned o1 = __shfl_xor(a1, x);
            unsigned o2 = __shfl_xor(a2, x);
            unsigned n1, n2;
            if (a1 < o1) { n1 = a1; n2 = (a2 < o1) ? a2 : o1; }
            else         { n1 = o1; n2 = (o2 < a1) ? o2 : a1; }
            a1 = n1; a2 = n2;
        }
        if (lane < 16) {
            int token = blk * 64 + nt * 16 + lane;
            *reinterpret_cast<uint2*>(top2 + ((size_t)wv * N_TOK + token) * 2) =
                make_uint2(a1, a2);
        }
    }
}

// ---------------- kernel 2: fused exact refine + gather + loss partials ----------------
__global__ __launch_bounds__(256)
void refgather_kernel(const float* __restrict__ z, const float* __restrict__ cb,
                      const float* __restrict__ cnorm, const unsigned* __restrict__ top2,
                      float* __restrict__ out, float* __restrict__ partials) {
    __shared__ float zsm[32][261];
    __shared__ float crows[32][257];
    __shared__ int cand[32][16];
    __shared__ int cnt[32];
    __shared__ u64 bestk[32];
    __shared__ int sidx[32];
    __shared__ float red[256];
    __shared__ int maxc;

    const int t = threadIdx.x;
    const int bh = blockIdx.x;  // 0..1023
    const int b = bh >> 5, h = bh & 31;
    const int n0 = b * 1024 + h * 32;
    const int w = t & 31, dg = t >> 5;

    {   // stage z rows (coalesced 128B segments)
        const float* zp = z + ((size_t)b << 18) + h * 32 + w;
#pragma unroll
        for (int i = 0; i < 32; ++i) {
            int d = dg * 32 + i;
            zsm[w][d] = zp[(size_t)d * 1024];
        }
    }
    if (t < 32) cnt[t] = 0;
    if (t == 0) maxc = 0;
    __syncthreads();

    const int tk = t >> 3, l8 = t & 7;
    {   // candidate collection from per-cblk top-2
        uint2 kk = *reinterpret_cast<const uint2*>(
            top2 + ((size_t)l8 * N_TOK + (n0 + tk)) * 2);
        unsigned mn = kk.x;  // k1 <= k2
#pragma unroll
        for (int x = 1; x < 8; x <<= 1) {
            unsigned o = __shfl_xor(mn, x);
            if (o < mn) mn = o;
        }
        float thr = unpackf(mn & 0xFFFFFC00u) + MARGIN;
        float da = unpackf(kk.x & 0xFFFFFC00u);
        if (da <= thr) { int p = atomicAdd(&cnt[tk], 1); cand[tk][p] = (int)(kk.x & 1023u); }
        float db = unpackf(kk.y & 0xFFFFFC00u);
        if (db <= thr) { int p = atomicAdd(&cnt[tk], 1); cand[tk][p] = (int)(kk.y & 1023u); }
    }
    __syncthreads();
    if (t < 32) atomicMax(&maxc, cnt[t]);
    __syncthreads();

    const int mc = maxc;
    u64 best = ~0ull;
    for (int ci = 0; ci < mc; ++ci) {
        if (ci < cnt[tk]) {
            int k = cand[tk][ci];
            const float* crow = cb + (size_t)k * 256;
            float s = 0.f;
#pragma unroll
            for (int j = 0; j < 32; ++j) {
                int d = j * 8 + l8;
                s = fmaf(zsm[tk][d], crow[d], s);
            }
#pragma unroll
            for (int x = 1; x < 8; x <<= 1) s += __shfl_xor(s, x);
            float d2 = cnorm[k] - 2.f * s;
            u64 key = ((u64)packf(d2) << 32) | (unsigned)k;
            if (key < best) best = key;
        }
    }
    if (l8 == 0) bestk[tk] = best;
    __syncthreads();
    if (t < 32) {
        int k = (int)(bestk[t] & 1023ull);
        sidx[t] = k;
        out[OUT_IDX_OFF + n0 + t] = (float)k;
    }
    __syncthreads();
    {   // stage chosen codebook rows (fp32)
        const int r = t & 31, q = t >> 5;
        const float4* src = reinterpret_cast<const float4*>(cb + (size_t)sidx[r] * 256 + q * 32);
#pragma unroll
        for (int j = 0; j < 8; ++j) {
            float4 v = src[j];
            int d = q * 32 + j * 4;
            crows[r][d] = v.x; crows[r][d + 1] = v.y;
            crows[r][d + 2] = v.z; crows[r][d + 3] = v.w;
        }
    }
    __syncthreads();
    float accl = 0.f;
    float* orow = out + ((size_t)b << 18) + h * 32 + w;
#pragma unroll
    for (int i = 0; i < 32; ++i) {
        const int d = dg * 32 + i;
        const float cv = crows[w][d];
        const float zv = zsm[w][d];
        orow[(size_t)d * 1024] = cv;
        const float df = cv - zv;
        accl += df * df;
    }
    red[t] = accl;
    __syncthreads();
    for (int s = 128; s > 0; s >>= 1) {
        if (t < s) red[t] += red[t + s];
        __syncthreads();
    }
    if (t == 0) partials[bh] = red[0];
}

// ---------------- kernel 3: deterministic final loss reduction ----------------
__global__ __launch_bounds__(256) void loss_kernel(const float* __restrict__ partials,
                                                   float* __restrict__ out) {
    __shared__ float red[256];
    const int t = threadIdx.x;
    float s = partials[t] + partials[t + 256] + partials[t + 512] + partials[t + 768];
    red[t] = s;
    __syncthreads();
    for (int st = 128; st > 0; st >>= 1) {
        if (t < st) red[t] += red[t + st];
        __syncthreads();
    }
    if (t == 0) out[OUT_LOSS_OFF] = red[0] * (1.25f / (float)Z_ELEMS);
}

extern "C" void kernel_launch(void* const* d_in, const int* in_sizes, int n_in,
                              void* d_out, int out_size, void* d_ws, size_t ws_size,
                              hipStream_t stream) {
    const float* z = (const float*)d_in[0];   // [32,256,32,32] f32
    const float* cb = (const float*)d_in[1];  // [1024,256] f32
    float* out = (float*)d_out;
    float* cnorm = (float*)((char*)d_ws + WS_CNORM_OFF);
    float* partials = (float*)((char*)d_ws + WS_PART_OFF);
    unsigned char* cbf = (unsigned char*)d_ws + WS_CBF_OFF;
    unsigned* top2 = (unsigned*)((char*)d_ws + WS_TOP2_OFF);

    prep_kernel<<<16, 256, 0, stream>>>(cb, cnorm, cbf);
    screen_kernel<<<512, 512, 0, stream>>>(z, cbf, cnorm, top2);
    refgather_kernel<<<1024, 256, 0, stream>>>(z, cb, cnorm, top2, out, partials);
    loss_kernel<<<1, 256, 0, stream>>>(partials, out);
}

// Round 11
// 77.425 us; speedup vs baseline: 2.1441x; 1.3528x over previous
//
#include <hip/hip_runtime.h>
#include <hip/hip_bf16.h>
#include <cstdint>

#define B_ 32
#define D_ 256
#define K_ 1024
#define N_TOK 32768
#define Z_ELEMS 8388608
#define OUT_IDX_OFF Z_ELEMS
#define OUT_LOSS_OFF (Z_ELEMS + N_TOK)

// ws layout (2.63 MB total — known-safe footprint):
//   [0,4096)             f32 cnorm[1024]
//   [4096,8192)          f32 partials[1024]
//   [8192,532480)        cb_frag bf16, fragment-order: g=((cblk*8+kc)*8+ct)*64+lane, 16B/g
//   [532480,2629632)     u32 top2[8 cblk][32768 tok][2]
#define WS_CNORM_OFF 0
#define WS_PART_OFF  4096
#define WS_CBF_OFF   8192
#define WS_TOP2_OFF  532480

#define MARGIN 1.25f

typedef __attribute__((ext_vector_type(8))) short short8v;
typedef __attribute__((ext_vector_type(4))) float f32x4;
typedef unsigned long long u64;

__device__ __forceinline__ unsigned short f2bf(float x) {
    unsigned u = __float_as_uint(x);
    return (unsigned short)((u + 0x7fffu + ((u >> 16) & 1u)) >> 16);  // RNE
}
__device__ __forceinline__ unsigned packf(float f) {
    unsigned u = __float_as_uint(f);
    return (u & 0x80000000u) ? ~u : (u | 0x80000000u);  // order-preserving bits
}
__device__ __forceinline__ float unpackf(unsigned p) {
    unsigned u = (p & 0x80000000u) ? (p & 0x7fffffffu) : ~p;
    return __uint_as_float(u);
}

// ---------------- kernel 0: cnorm (fp32) + cb -> bf16 fragment order ----------------
__global__ __launch_bounds__(256)
void prep_kernel(const float* __restrict__ cb, float* __restrict__ cnorm,
                 unsigned char* __restrict__ cbf) {
    const int t = threadIdx.x;
    const int blk = blockIdx.x;  // 16 blocks
    {   // cnorm: 64 codes per block, 4 threads each
        int k = blk * 64 + (t >> 2);
        int part = t & 3;
        const float4* row = reinterpret_cast<const float4*>(cb + k * D_);
        float s = 0.f;
#pragma unroll
        for (int j = 0; j < 16; ++j) {
            float4 v = row[part * 16 + j];
            s += v.x * v.x + v.y * v.y + v.z * v.z + v.w * v.w;
        }
        s += __shfl_xor(s, 1);
        s += __shfl_xor(s, 2);
        if (part == 0) cnorm[k] = s;
    }
#pragma unroll
    for (int w = 0; w < 8; ++w) {
        int g = blk * 2048 + w * 256 + t;
        int lane = g & 63, ct = (g >> 6) & 7, kc = (g >> 9) & 7, cblk = g >> 12;
        int code = cblk * 128 + ct * 16 + (lane & 15);
        int d0 = kc * 32 + (lane >> 4) * 8;
        const float* src = cb + code * 256 + d0;
        float4 a = *reinterpret_cast<const float4*>(src);
        float4 b2 = *reinterpret_cast<const float4*>(src + 4);
        uint4 pk;
        pk.x = (unsigned)f2bf(a.x) | ((unsigned)f2bf(a.y) << 16);
        pk.y = (unsigned)f2bf(a.z) | ((unsigned)f2bf(a.w) << 16);
        pk.z = (unsigned)f2bf(b2.x) | ((unsigned)f2bf(b2.y) << 16);
        pk.w = (unsigned)f2bf(b2.z) | ((unsigned)f2bf(b2.w) << 16);
        *reinterpret_cast<uint4*>(cbf + (size_t)g * 16) = pk;
    }
}

// ---------------- kernel 1: MFMA screen, in-kernel z staging ----------------
// 512 blocks x 256 thr (4 waves). Block = 64 tok x 1024 codes; wave wv = cblks {2wv,2wv+1}.
// Per cblk: 2 phases x 64 codes, acc[4][4]=64 regs. NO min-waves bound (r8-r10 suspect).
__global__ __launch_bounds__(256)
void mm_kernel(const float* __restrict__ z, const unsigned char* __restrict__ cbf,
               const float* __restrict__ cnorm, unsigned* __restrict__ top2) {
    __shared__ __align__(16) unsigned char zfB[32768];
    __shared__ float cns[1024];

    const int t = threadIdx.x;
    const int lane = t & 63;
    const int wv = t >> 6;
    const int blk = blockIdx.x;
    const int b = blk >> 4;
    const int hw0 = (blk & 15) << 6;
    const float* zb = z + ((size_t)b << 18) + hw0;

    for (int i = t; i < 1024; i += 256) cns[i] = cnorm[i];

    {   // stage 64 tok x 256 d -> bf16 fragments in LDS (round-4-verified formula)
        const int tok = t & 63;
        const int dseg = t >> 6;   // 4 segs x 64 d
#pragma unroll
        for (int u = 0; u < 8; ++u) {
            int d0 = dseg * 64 + u * 8;
            float v[8];
#pragma unroll
            for (int j = 0; j < 8; ++j) v[j] = zb[(size_t)(d0 + j) * 1024 + tok];
            uint4 pk;
            pk.x = (unsigned)f2bf(v[0]) | ((unsigned)f2bf(v[1]) << 16);
            pk.y = (unsigned)f2bf(v[2]) | ((unsigned)f2bf(v[3]) << 16);
            pk.z = (unsigned)f2bf(v[4]) | ((unsigned)f2bf(v[5]) << 16);
            pk.w = (unsigned)f2bf(v[6]) | ((unsigned)f2bf(v[7]) << 16);
            int kc = d0 >> 5;
            *reinterpret_cast<uint4*>(zfB + (kc * 4 + (tok >> 4)) * 1024 +
                                      ((u & 3) * 16 + (tok & 15)) * 16) = pk;
        }
    }
    __syncthreads();

    const int rbase = (lane >> 4) << 2;
    const unsigned char* zrd = zfB + lane * 16;

    for (int cb2 = 0; cb2 < 2; ++cb2) {
        const int cblk = wv * 2 + cb2;
        const unsigned char* abase = cbf + (size_t)cblk * 65536 + lane * 16;

        unsigned k1[4], k2[4];
#pragma unroll
        for (int nt = 0; nt < 4; ++nt) { k1[nt] = 0xFFFFFFFFu; k2[nt] = 0xFFFFFFFFu; }

        for (int p = 0; p < 2; ++p) {   // 64-code phase
            f32x4 acc[4][4];
#pragma unroll
            for (int mt = 0; mt < 4; ++mt)
#pragma unroll
                for (int nt = 0; nt < 4; ++nt) acc[mt][nt] = (f32x4){0.f, 0.f, 0.f, 0.f};

#pragma unroll
            for (int kc = 0; kc < 8; ++kc) {
                short8v bfv[4];
#pragma unroll
                for (int nt = 0; nt < 4; ++nt)
                    bfv[nt] = *reinterpret_cast<const short8v*>(zrd + (kc * 4 + nt) * 1024);
                short8v af[4];
#pragma unroll
                for (int mt = 0; mt < 4; ++mt)
                    af[mt] = *reinterpret_cast<const short8v*>(
                        abase + (kc * 8 + p * 4 + mt) * 1024);
#pragma unroll
                for (int mt = 0; mt < 4; ++mt)
#pragma unroll
                    for (int nt = 0; nt < 4; ++nt)
                        acc[mt][nt] = __builtin_amdgcn_mfma_f32_16x16x32_bf16(
                            af[mt], bfv[nt], acc[mt][nt], 0, 0, 0);
            }

            // fold this phase's 64 codes into the per-cblk running top-2
#pragma unroll
            for (int nt = 0; nt < 4; ++nt) {
#pragma unroll
                for (int mt = 0; mt < 4; ++mt) {
#pragma unroll
                    for (int r = 0; r < 4; ++r) {
                        int code = cblk * 128 + (p * 4 + mt) * 16 + rbase + r;
                        float d2a = fmaf(-2.0f, acc[mt][nt][r], cns[code]);
                        unsigned key = (packf(d2a) & 0xFFFFFC00u) | (unsigned)code;
                        if (key < k1[nt]) { k2[nt] = k1[nt]; k1[nt] = key; }
                        else if (key < k2[nt]) { k2[nt] = key; }
                    }
                }
            }
        }

        // reduce across the 4 row-groups and write this cblk's top-2
#pragma unroll
        for (int nt = 0; nt < 4; ++nt) {
            unsigned a1 = k1[nt], a2 = k2[nt];
#pragma unroll
            for (int x = 16; x <= 32; x <<= 1) {
                unsigned o1 = __shfl_xor(a1, x);
                unsigned o2 = __shfl_xor(a2, x);
                unsigned n1, n2;
                if (a1 < o1) { n1 = a1; n2 = (a2 < o1) ? a2 : o1; }
                else         { n1 = o1; n2 = (o2 < a1) ? o2 : a1; }
                a1 = n1; a2 = n2;
            }
            if (lane < 16) {
                int token = blk * 64 + nt * 16 + lane;
                *reinterpret_cast<uint2*>(top2 + ((size_t)cblk * N_TOK + token) * 2) =
                    make_uint2(a1, a2);
            }
        }
    }
}

// ---------------- kernel 2: fused exact refine + gather + loss partials ----------------
__global__ __launch_bounds__(256)
void refgather_kernel(const float* __restrict__ z, const float* __restrict__ cb,
                      const float* __restrict__ cnorm, const unsigned* __restrict__ top2,
                      float* __restrict__ out, float* __restrict__ partials) {
    __shared__ float zsm[32][261];
    __shared__ float crows[32][257];
    __shared__ int cand[32][16];
    __shared__ int cnt[32];
    __shared__ u64 bestk[32];
    __shared__ int sidx[32];
    __shared__ float red[256];
    __shared__ int maxc;

    const int t = threadIdx.x;
    const int bh = blockIdx.x;  // 0..1023
    const int b = bh >> 5, h = bh & 31;
    const int n0 = b * 1024 + h * 32;
    const int w = t & 31, dg = t >> 5;

    {   // stage z rows (coalesced 128B segments)
        const float* zp = z + ((size_t)b << 18) + h * 32 + w;
#pragma unroll
        for (int i = 0; i < 32; ++i) {
            int d = dg * 32 + i;
            zsm[w][d] = zp[(size_t)d * 1024];
        }
    }
    if (t < 32) cnt[t] = 0;
    if (t == 0) maxc = 0;
    __syncthreads();

    const int tk = t >> 3, l8 = t & 7;
    {   // candidate collection from per-cblk top-2
        uint2 kk = *reinterpret_cast<const uint2*>(
            top2 + ((size_t)l8 * N_TOK + (n0 + tk)) * 2);
        unsigned mn = kk.x;  // k1 <= k2
#pragma unroll
        for (int x = 1; x < 8; x <<= 1) {
            unsigned o = __shfl_xor(mn, x);
            if (o < mn) mn = o;
        }
        float thr = unpackf(mn & 0xFFFFFC00u) + MARGIN;
        float da = unpackf(kk.x & 0xFFFFFC00u);
        if (da <= thr) { int p = atomicAdd(&cnt[tk], 1); cand[tk][p] = (int)(kk.x & 1023u); }
        float db = unpackf(kk.y & 0xFFFFFC00u);
        if (db <= thr) { int p = atomicAdd(&cnt[tk], 1); cand[tk][p] = (int)(kk.y & 1023u); }
    }
    __syncthreads();
    if (t < 32) atomicMax(&maxc, cnt[t]);
    __syncthreads();

    const int mc = maxc;
    u64 best = ~0ull;
    for (int ci = 0; ci < mc; ++ci) {
        if (ci < cnt[tk]) {
            int k = cand[tk][ci];
            const float* crow = cb + (size_t)k * 256;
            float s = 0.f;
#pragma unroll
            for (int j = 0; j < 32; ++j) {
                int d = j * 8 + l8;
                s = fmaf(zsm[tk][d], crow[d], s);
            }
#pragma unroll
            for (int x = 1; x < 8; x <<= 1) s += __shfl_xor(s, x);
            float d2 = cnorm[k] - 2.f * s;
            u64 key = ((u64)packf(d2) << 32) | (unsigned)k;
            if (key < best) best = key;
        }
    }
    if (l8 == 0) bestk[tk] = best;
    __syncthreads();
    if (t < 32) {
        int k = (int)(bestk[t] & 1023ull);
        sidx[t] = k;
        out[OUT_IDX_OFF + n0 + t] = (float)k;
    }
    __syncthreads();
    {   // stage chosen codebook rows (fp32)
        const int r = t & 31, q = t >> 5;
        const float4* src = reinterpret_cast<const float4*>(cb + (size_t)sidx[r] * 256 + q * 32);
#pragma unroll
        for (int j = 0; j < 8; ++j) {
            float4 v = src[j];
            int d = q * 32 + j * 4;
            crows[r][d] = v.x; crows[r][d + 1] = v.y;
            crows[r][d + 2] = v.z; crows[r][d + 3] = v.w;
        }
    }
    __syncthreads();
    float accl = 0.f;
    float* orow = out + ((size_t)b << 18) + h * 32 + w;
#pragma unroll
    for (int i = 0; i < 32; ++i) {
        const int d = dg * 32 + i;
        const float cv = crows[w][d];
        const float zv = zsm[w][d];
        orow[(size_t)d * 1024] = cv;
        const float df = cv - zv;
        accl += df * df;
    }
    red[t] = accl;
    __syncthreads();
    for (int s = 128; s > 0; s >>= 1) {
        if (t < s) red[t] += red[t + s];
        __syncthreads();
    }
    if (t == 0) partials[bh] = red[0];
}

// ---------------- kernel 3: deterministic final loss reduction ----------------
__global__ __launch_bounds__(256) void loss_kernel(const float* __restrict__ partials,
                                                   float* __restrict__ out) {
    __shared__ float red[256];
    const int t = threadIdx.x;
    float s = partials[t] + partials[t + 256] + partials[t + 512] + partials[t + 768];
    red[t] = s;
    __syncthreads();
    for (int st = 128; st > 0; st >>= 1) {
        if (t < st) red[t] += red[t + st];
        __syncthreads();
    }
    if (t == 0) out[OUT_LOSS_OFF] = red[0] * (1.25f / (float)Z_ELEMS);
}

extern "C" void kernel_launch(void* const* d_in, const int* in_sizes, int n_in,
                              void* d_out, int out_size, void* d_ws, size_t ws_size,
                              hipStream_t stream) {
    const float* z = (const float*)d_in[0];   // [32,256,32,32] f32
    const float* cb = (const float*)d_in[1];  // [1024,256] f32
    float* out = (float*)d_out;
    float* cnorm = (float*)((char*)d_ws + WS_CNORM_OFF);
    float* partials = (float*)((char*)d_ws + WS_PART_OFF);
    unsigned char* cbf = (unsigned char*)d_ws + WS_CBF_OFF;
    unsigned* top2 = (unsigned*)((char*)d_ws + WS_TOP2_OFF);

    prep_kernel<<<16, 256, 0, stream>>>(cb, cnorm, cbf);
    mm_kernel<<<512, 256, 0, stream>>>(z, cbf, cnorm, top2);
    refgather_kernel<<<1024, 256, 0, stream>>>(z, cb, cnorm, top2, out, partials);
    loss_kernel<<<1, 256, 0, stream>>>(partials, out);
}

// Round 12
// 75.217 us; speedup vs baseline: 2.2071x; 1.0294x over previous
//
#include <hip/hip_runtime.h>
#include <hip/hip_bf16.h>
#include <cstdint>

#define B_ 32
#define D_ 256
#define K_ 1024
#define N_TOK 32768
#define Z_ELEMS 8388608
#define OUT_IDX_OFF Z_ELEMS
#define OUT_LOSS_OFF (Z_ELEMS + N_TOK)

// ws layout (2.63 MB total — known-safe footprint):
//   [0,4096)             f32 cnorm[1024]
//   [4096,8192)          f32 partials[1024]
//   [8192,532480)        cb_frag bf16, fragment-order: chunk s=cblk*8+kc at s*8192, 16B/frag-lane
//   [532480,2629632)     u32 top2[8 cblk][32768 tok][2]
#define WS_CNORM_OFF 0
#define WS_PART_OFF  4096
#define WS_CBF_OFF   8192
#define WS_TOP2_OFF  532480

#define MARGIN 1.25f

typedef __attribute__((ext_vector_type(8))) short short8v;
typedef __attribute__((ext_vector_type(4))) float f32x4;
typedef unsigned long long u64;

__device__ __forceinline__ unsigned short f2bf(float x) {
    unsigned u = __float_as_uint(x);
    return (unsigned short)((u + 0x7fffu + ((u >> 16) & 1u)) >> 16);  // RNE
}
__device__ __forceinline__ unsigned packf(float f) {
    unsigned u = __float_as_uint(f);
    return (u & 0x80000000u) ? ~u : (u | 0x80000000u);  // order-preserving bits
}
__device__ __forceinline__ float unpackf(unsigned p) {
    unsigned u = (p & 0x80000000u) ? (p & 0x7fffffffu) : ~p;
    return __uint_as_float(u);
}

// ---------------- kernel 0: cnorm (fp32) + cb -> bf16 fragment order ----------------
__global__ __launch_bounds__(256)
void prep_kernel(const float* __restrict__ cb, float* __restrict__ cnorm,
                 unsigned char* __restrict__ cbf) {
    const int t = threadIdx.x;
    const int blk = blockIdx.x;  // 16 blocks
    {   // cnorm: 64 codes per block, 4 threads each
        int k = blk * 64 + (t >> 2);
        int part = t & 3;
        const float4* row = reinterpret_cast<const float4*>(cb + k * D_);
        float s = 0.f;
#pragma unroll
        for (int j = 0; j < 16; ++j) {
            float4 v = row[part * 16 + j];
            s += v.x * v.x + v.y * v.y + v.z * v.z + v.w * v.w;
        }
        s += __shfl_xor(s, 1);
        s += __shfl_xor(s, 2);
        if (part == 0) cnorm[k] = s;
    }
#pragma unroll
    for (int w = 0; w < 8; ++w) {
        int g = blk * 2048 + w * 256 + t;
        int lane = g & 63, ct = (g >> 6) & 7, kc = (g >> 9) & 7, cblk = g >> 12;
        int code = cblk * 128 + ct * 16 + (lane & 15);
        int d0 = kc * 32 + (lane >> 4) * 8;
        const float* src = cb + code * 256 + d0;
        float4 a = *reinterpret_cast<const float4*>(src);
        float4 b2 = *reinterpret_cast<const float4*>(src + 4);
        uint4 pk;
        pk.x = (unsigned)f2bf(a.x) | ((unsigned)f2bf(a.y) << 16);
        pk.y = (unsigned)f2bf(a.z) | ((unsigned)f2bf(a.w) << 16);
        pk.z = (unsigned)f2bf(b2.x) | ((unsigned)f2bf(b2.y) << 16);
        pk.w = (unsigned)f2bf(b2.z) | ((unsigned)f2bf(b2.w) << 16);
        *reinterpret_cast<uint4*>(cbf + (size_t)g * 16) = pk;
    }
}

// ---------------- kernel 1: MFMA screen, A double-buffered through LDS ----------------
// 512 blocks x 256 thr (4 waves). Block = 64 tok x 1024 codes; wave wv = tokens wv*16..+15.
// 64 steps (cblk,kc): async-stage next 8KB A-chunk to LDS while MFMA-ing current from LDS.
__global__ __launch_bounds__(256)
void mm_kernel(const float* __restrict__ z, const unsigned char* __restrict__ cbf,
               const float* __restrict__ cnorm, unsigned* __restrict__ top2) {
    __shared__ __align__(16) unsigned char zfB[32768];   // z fragments (r11-verified layout)
    __shared__ __align__(16) unsigned char Abuf[16384];  // 2 x 8KB A-chunk double buffer
    __shared__ float cns[1024];

    const int t = threadIdx.x;
    const int lane = t & 63;
    const int wv = t >> 6;
    const int blk = blockIdx.x;
    const int b = blk >> 4;
    const int hw0 = (blk & 15) << 6;
    const float* zb = z + ((size_t)b << 18) + hw0;
    const uint4* cbf4 = reinterpret_cast<const uint4*>(cbf);

    // prologue: chunk 0 loads issued first (latency hides under z staging)
    uint4 c0a = cbf4[t];
    uint4 c0b = cbf4[256 + t];

    for (int i = t; i < 1024; i += 256) cns[i] = cnorm[i];

    {   // stage 64 tok x 256 d -> bf16 fragments in LDS (round-4/11-verified formula)
        const int tok = t & 63;
        const int dseg = t >> 6;   // 4 segs x 64 d
#pragma unroll
        for (int u = 0; u < 8; ++u) {
            int d0 = dseg * 64 + u * 8;
            float v[8];
#pragma unroll
            for (int j = 0; j < 8; ++j) v[j] = zb[(size_t)(d0 + j) * 1024 + tok];
            uint4 pk;
            pk.x = (unsigned)f2bf(v[0]) | ((unsigned)f2bf(v[1]) << 16);
            pk.y = (unsigned)f2bf(v[2]) | ((unsigned)f2bf(v[3]) << 16);
            pk.z = (unsigned)f2bf(v[4]) | ((unsigned)f2bf(v[5]) << 16);
            pk.w = (unsigned)f2bf(v[6]) | ((unsigned)f2bf(v[7]) << 16);
            int kc = d0 >> 5;
            *reinterpret_cast<uint4*>(zfB + (kc * 4 + (tok >> 4)) * 1024 +
                                      ((u & 3) * 16 + (tok & 15)) * 16) = pk;
        }
    }
    {   // write chunk 0 into buf 0
        uint4* d = reinterpret_cast<uint4*>(Abuf);
        d[t] = c0a;
        d[256 + t] = c0b;
    }
    __syncthreads();

    const int rbase = (lane >> 4) << 2;

    for (int cblk = 0; cblk < 8; ++cblk) {
        f32x4 acc[8];
#pragma unroll
        for (int mt = 0; mt < 8; ++mt) acc[mt] = (f32x4){0.f, 0.f, 0.f, 0.f};

        for (int kc = 0; kc < 8; ++kc) {
            const int s = cblk * 8 + kc;
            // issue next chunk's global loads (complete during compute below)
            uint4 na, nb;
            if (s < 63) {
                na = cbf4[(size_t)(s + 1) * 512 + t];
                nb = cbf4[(size_t)(s + 1) * 512 + 256 + t];
            }
            // compute current chunk from LDS
            const unsigned char* ab = Abuf + (s & 1) * 8192 + lane * 16;
            short8v bfv = *reinterpret_cast<const short8v*>(
                zfB + (kc * 4 + wv) * 1024 + lane * 16);
#pragma unroll
            for (int mt = 0; mt < 8; ++mt) {
                short8v af = *reinterpret_cast<const short8v*>(ab + mt * 1024);
                acc[mt] = __builtin_amdgcn_mfma_f32_16x16x32_bf16(af, bfv, acc[mt], 0, 0, 0);
            }
            if (kc == 7) {
                // fold this cblk's 128 codes into per-token top-2 and write out
                unsigned k1 = 0xFFFFFFFFu, k2 = 0xFFFFFFFFu;
#pragma unroll
                for (int mt = 0; mt < 8; ++mt) {
#pragma unroll
                    for (int r = 0; r < 4; ++r) {
                        int code = cblk * 128 + mt * 16 + rbase + r;
                        float d2a = fmaf(-2.0f, acc[mt][r], cns[code]);
                        unsigned key = (packf(d2a) & 0xFFFFFC00u) | (unsigned)code;
                        if (key < k1) { k2 = k1; k1 = key; }
                        else if (key < k2) { k2 = key; }
                    }
                }
#pragma unroll
                for (int x = 16; x <= 32; x <<= 1) {
                    unsigned o1 = __shfl_xor(k1, x);
                    unsigned o2 = __shfl_xor(k2, x);
                    unsigned n1, n2;
                    if (k1 < o1) { n1 = k1; n2 = (k2 < o1) ? k2 : o1; }
                    else         { n1 = o1; n2 = (o2 < k1) ? o2 : k1; }
                    k1 = n1; k2 = n2;
                }
                if (lane < 16) {
                    int token = blk * 64 + wv * 16 + lane;
                    *reinterpret_cast<uint2*>(top2 + ((size_t)cblk * N_TOK + token) * 2) =
                        make_uint2(k1, k2);
                }
            }
            // late write of the staged chunk (vmcnt wait lands here, after compute)
            if (s < 63) {
                uint4* d = reinterpret_cast<uint4*>(Abuf + ((s + 1) & 1) * 8192);
                d[t] = na;
                d[256 + t] = nb;
            }
            __syncthreads();
        }
    }
}

// ---------------- kernel 2: fused exact refine + gather + loss partials ----------------
__global__ __launch_bounds__(256)
void refgather_kernel(const float* __restrict__ z, const float* __restrict__ cb,
                      const float* __restrict__ cnorm, const unsigned* __restrict__ top2,
                      float* __restrict__ out, float* __restrict__ partials) {
    __shared__ float zsm[32][261];
    __shared__ float crows[32][257];
    __shared__ int cand[32][16];
    __shared__ int cnt[32];
    __shared__ u64 bestk[32];
    __shared__ int sidx[32];
    __shared__ float red[256];
    __shared__ int maxc;

    const int t = threadIdx.x;
    const int bh = blockIdx.x;  // 0..1023
    const int b = bh >> 5, h = bh & 31;
    const int n0 = b * 1024 + h * 32;
    const int w = t & 31, dg = t >> 5;

    {   // stage z rows (coalesced 128B segments)
        const float* zp = z + ((size_t)b << 18) + h * 32 + w;
#pragma unroll
        for (int i = 0; i < 32; ++i) {
            int d = dg * 32 + i;
            zsm[w][d] = zp[(size_t)d * 1024];
        }
    }
    if (t < 32) cnt[t] = 0;
    if (t == 0) maxc = 0;
    __syncthreads();

    const int tk = t >> 3, l8 = t & 7;
    {   // candidate collection from per-cblk top-2
        uint2 kk = *reinterpret_cast<const uint2*>(
            top2 + ((size_t)l8 * N_TOK + (n0 + tk)) * 2);
        unsigned mn = kk.x;  // k1 <= k2
#pragma unroll
        for (int x = 1; x < 8; x <<= 1) {
            unsigned o = __shfl_xor(mn, x);
            if (o < mn) mn = o;
        }
        float thr = unpackf(mn & 0xFFFFFC00u) + MARGIN;
        float da = unpackf(kk.x & 0xFFFFFC00u);
        if (da <= thr) { int p = atomicAdd(&cnt[tk], 1); cand[tk][p] = (int)(kk.x & 1023u); }
        float db = unpackf(kk.y & 0xFFFFFC00u);
        if (db <= thr) { int p = atomicAdd(&cnt[tk], 1); cand[tk][p] = (int)(kk.y & 1023u); }
    }
    __syncthreads();
    if (t < 32) atomicMax(&maxc, cnt[t]);
    __syncthreads();

    const int mc = maxc;
    u64 best = ~0ull;
    for (int ci = 0; ci < mc; ++ci) {
        if (ci < cnt[tk]) {
            int k = cand[tk][ci];
            const float* crow = cb + (size_t)k * 256;
            float s = 0.f;
#pragma unroll
            for (int j = 0; j < 32; ++j) {
                int d = j * 8 + l8;
                s = fmaf(zsm[tk][d], crow[d], s);
            }
#pragma unroll
            for (int x = 1; x < 8; x <<= 1) s += __shfl_xor(s, x);
            float d2 = cnorm[k] - 2.f * s;
            u64 key = ((u64)packf(d2) << 32) | (unsigned)k;
            if (key < best) best = key;
        }
    }
    if (l8 == 0) bestk[tk] = best;
    __syncthreads();
    if (t < 32) {
        int k = (int)(bestk[t] & 1023ull);
        sidx[t] = k;
        out[OUT_IDX_OFF + n0 + t] = (float)k;
    }
    __syncthreads();
    {   // stage chosen codebook rows (fp32)
        const int r = t & 31, q = t >> 5;
        const float4* src = reinterpret_cast<const float4*>(cb + (size_t)sidx[r] * 256 + q * 32);
#pragma unroll
        for (int j = 0; j < 8; ++j) {
            float4 v = src[j];
            int d = q * 32 + j * 4;
            crows[r][d] = v.x; crows[r][d + 1] = v.y;
            crows[r][d + 2] = v.z; crows[r][d + 3] = v.w;
        }
    }
    __syncthreads();
    float accl = 0.f;
    float* orow = out + ((size_t)b << 18) + h * 32 + w;
#pragma unroll
    for (int i = 0; i < 32; ++i) {
        const int d = dg * 32 + i;
        const float cv = crows[w][d];
        const float zv = zsm[w][d];
        orow[(size_t)d * 1024] = cv;
        const float df = cv - zv;
        accl += df * df;
    }
    red[t] = accl;
    __syncthreads();
    for (int s = 128; s > 0; s >>= 1) {
        if (t < s) red[t] += red[t + s];
        __syncthreads();
    }
    if (t == 0) partials[bh] = red[0];
}

// ---------------- kernel 3: deterministic final loss reduction ----------------
__global__ __launch_bounds__(256) void loss_kernel(const float* __restrict__ partials,
                                                   float* __restrict__ out) {
    __shared__ float red[256];
    const int t = threadIdx.x;
    float s = partials[t] + partials[t + 256] + partials[t + 512] + partials[t + 768];
    red[t] = s;
    __syncthreads();
    for (int st = 128; st > 0; st >>= 1) {
        if (t < st) red[t] += red[t + st];
        __syncthreads();
    }
    if (t == 0) out[OUT_LOSS_OFF] = red[0] * (1.25f / (float)Z_ELEMS);
}

extern "C" void kernel_launch(void* const* d_in, const int* in_sizes, int n_in,
                              void* d_out, int out_size, void* d_ws, size_t ws_size,
                              hipStream_t stream) {
    const float* z = (const float*)d_in[0];   // [32,256,32,32] f32
    const float* cb = (const float*)d_in[1];  // [1024,256] f32
    float* out = (float*)d_out;
    float* cnorm = (float*)((char*)d_ws + WS_CNORM_OFF);
    float* partials = (float*)((char*)d_ws + WS_PART_OFF);
    unsigned char* cbf = (unsigned char*)d_ws + WS_CBF_OFF;
    unsigned* top2 = (unsigned*)((char*)d_ws + WS_TOP2_OFF);

    prep_kernel<<<16, 256, 0, stream>>>(cb, cnorm, cbf);
    mm_kernel<<<512, 256, 0, stream>>>(z, cbf, cnorm, top2);
    refgather_kernel<<<1024, 256, 0, stream>>>(z, cb, cnorm, top2, out, partials);
    loss_kernel<<<1, 256, 0, stream>>>(partials, out);
}

// Round 13
// 69.948 us; speedup vs baseline: 2.3733x; 1.0753x over previous
//
#include <hip/hip_runtime.h>
#include <hip/hip_bf16.h>
#include <cstdint>

#define B_ 32
#define D_ 256
#define K_ 1024
#define N_TOK 32768
#define Z_ELEMS 8388608
#define OUT_IDX_OFF Z_ELEMS
#define OUT_LOSS_OFF (Z_ELEMS + N_TOK)

// ws layout (2.63 MB total — known-safe footprint):
//   [0,4096)             f32 cnorm[1024]
//   [4096,8192)          f32 partials[1024]
//   [8192,532480)        cb_frag bf16: frag(cblk,kc,ct) at (cblk*8+kc)*8192 + ct*1024 + lane*16
//   [532480,2629632)     u32 top2[8 cblk][32768 tok][2]
#define WS_CNORM_OFF 0
#define WS_PART_OFF  4096
#define WS_CBF_OFF   8192
#define WS_TOP2_OFF  532480

#define MARGIN 1.25f

typedef __attribute__((ext_vector_type(8))) short short8v;
typedef __attribute__((ext_vector_type(4))) float f32x4;
typedef unsigned long long u64;

__device__ __forceinline__ unsigned short f2bf(float x) {
    unsigned u = __float_as_uint(x);
    return (unsigned short)((u + 0x7fffu + ((u >> 16) & 1u)) >> 16);  // RNE
}
__device__ __forceinline__ unsigned packf(float f) {
    unsigned u = __float_as_uint(f);
    return (u & 0x80000000u) ? ~u : (u | 0x80000000u);  // order-preserving bits
}
__device__ __forceinline__ float unpackf(unsigned p) {
    unsigned u = (p & 0x80000000u) ? (p & 0x7fffffffu) : ~p;
    return __uint_as_float(u);
}

// ---------------- kernel 0: cnorm (fp32) + cb -> bf16 fragment order ----------------
__global__ __launch_bounds__(256)
void prep_kernel(const float* __restrict__ cb, float* __restrict__ cnorm,
                 unsigned char* __restrict__ cbf) {
    const int t = threadIdx.x;
    const int blk = blockIdx.x;  // 16 blocks
    {   // cnorm: 64 codes per block, 4 threads each
        int k = blk * 64 + (t >> 2);
        int part = t & 3;
        const float4* row = reinterpret_cast<const float4*>(cb + k * D_);
        float s = 0.f;
#pragma unroll
        for (int j = 0; j < 16; ++j) {
            float4 v = row[part * 16 + j];
            s += v.x * v.x + v.y * v.y + v.z * v.z + v.w * v.w;
        }
        s += __shfl_xor(s, 1);
        s += __shfl_xor(s, 2);
        if (part == 0) cnorm[k] = s;
    }
#pragma unroll
    for (int w = 0; w < 8; ++w) {
        int g = blk * 2048 + w * 256 + t;
        int lane = g & 63, ct = (g >> 6) & 7, kc = (g >> 9) & 7, cblk = g >> 12;
        int code = cblk * 128 + ct * 16 + (lane & 15);
        int d0 = kc * 32 + (lane >> 4) * 8;
        const float* src = cb + code * 256 + d0;
        float4 a = *reinterpret_cast<const float4*>(src);
        float4 b2 = *reinterpret_cast<const float4*>(src + 4);
        uint4 pk;
        pk.x = (unsigned)f2bf(a.x) | ((unsigned)f2bf(a.y) << 16);
        pk.y = (unsigned)f2bf(a.z) | ((unsigned)f2bf(a.w) << 16);
        pk.z = (unsigned)f2bf(b2.x) | ((unsigned)f2bf(b2.y) << 16);
        pk.w = (unsigned)f2bf(b2.z) | ((unsigned)f2bf(b2.w) << 16);
        *reinterpret_cast<uint4*>(cbf + (size_t)g * 16) = pk;
    }
}

// ---------------- kernel 1: MFMA screen, 8 independent waves/block ----------------
// 512 blocks x 512 thr. Block = 64 tok x 1024 codes.
// Wave wv: token-half th=wv&1 (32 tok), code-quarter cq=wv>>1 (2 cblks).
// A direct from L2 (r4 path); z from LDS (read-only after one barrier); NO inner barriers.
__global__
void mm_kernel(const float* __restrict__ z, const unsigned char* __restrict__ cbf,
               const float* __restrict__ cnorm, unsigned* __restrict__ top2) {
    __shared__ __align__(16) unsigned char zfB[32768];  // [kc 8][ntg 4][lane 64][16B]
    __shared__ float cns[1024];

    const int t = threadIdx.x;
    const int lane = t & 63;
    const int wv = t >> 6;          // 0..7
    const int th = wv & 1;          // token half
    const int cq = wv >> 1;         // code quarter
    const int blk = blockIdx.x;
    const int b = blk >> 4;
    const int hw0 = (blk & 15) << 6;
    const float* zb = z + ((size_t)b << 18) + hw0;

    if (t < 512) { cns[t] = cnorm[t]; cns[512 + t] = cnorm[512 + t]; }

    {   // stage 64 tok x 256 d -> bf16 fragments in LDS (r7-verified 512-thr staging)
        const int tok = t & 63;
        const int kc = t >> 6;      // 0..7: 32-d block
#pragma unroll
        for (int u = 0; u < 4; ++u) {
            int d0 = kc * 32 + u * 8;
            float v[8];
#pragma unroll
            for (int j = 0; j < 8; ++j) v[j] = zb[(size_t)(d0 + j) * 1024 + tok];
            uint4 pk;
            pk.x = (unsigned)f2bf(v[0]) | ((unsigned)f2bf(v[1]) << 16);
            pk.y = (unsigned)f2bf(v[2]) | ((unsigned)f2bf(v[3]) << 16);
            pk.z = (unsigned)f2bf(v[4]) | ((unsigned)f2bf(v[5]) << 16);
            pk.w = (unsigned)f2bf(v[6]) | ((unsigned)f2bf(v[7]) << 16);
            *reinterpret_cast<uint4*>(zfB + (kc * 4 + (tok >> 4)) * 1024 +
                                      (u * 16 + (tok & 15)) * 16) = pk;
        }
    }
    __syncthreads();

    const int rbase = (lane >> 4) << 2;
    // this wave's two z-fragment base pointers (ntg = th*2 + {0,1})
    const unsigned char* zrd0 = zfB + (th * 2 + 0) * 1024 + lane * 16;
    const unsigned char* zrd1 = zfB + (th * 2 + 1) * 1024 + lane * 16;

#pragma unroll
    for (int cb2 = 0; cb2 < 2; ++cb2) {
        const int cblk = cq * 2 + cb2;
        const unsigned char* abase = cbf + (size_t)cblk * 65536 + lane * 16;

        f32x4 acc[8][2];
#pragma unroll
        for (int mt = 0; mt < 8; ++mt) {
            acc[mt][0] = (f32x4){0.f, 0.f, 0.f, 0.f};
            acc[mt][1] = (f32x4){0.f, 0.f, 0.f, 0.f};
        }

#pragma unroll
        for (int kc = 0; kc < 8; ++kc) {
            short8v bf0 = *reinterpret_cast<const short8v*>(zrd0 + kc * 4096);
            short8v bf1 = *reinterpret_cast<const short8v*>(zrd1 + kc * 4096);
#pragma unroll
            for (int mt = 0; mt < 8; ++mt) {
                short8v af = *reinterpret_cast<const short8v*>(abase + (kc * 8 + mt) * 1024);
                acc[mt][0] = __builtin_amdgcn_mfma_f32_16x16x32_bf16(af, bf0, acc[mt][0], 0, 0, 0);
                acc[mt][1] = __builtin_amdgcn_mfma_f32_16x16x32_bf16(af, bf1, acc[mt][1], 0, 0, 0);
            }
        }

        // epilogue: per-token top-2 over this cblk's 128 codes
#pragma unroll
        for (int nt = 0; nt < 2; ++nt) {
            unsigned k1 = 0xFFFFFFFFu, k2 = 0xFFFFFFFFu;
#pragma unroll
            for (int mt = 0; mt < 8; ++mt) {
#pragma unroll
                for (int r = 0; r < 4; ++r) {
                    int code = cblk * 128 + mt * 16 + rbase + r;
                    float d2a = fmaf(-2.0f, acc[mt][nt][r], cns[code]);
                    unsigned key = (packf(d2a) & 0xFFFFFC00u) | (unsigned)code;
                    if (key < k1) { k2 = k1; k1 = key; }
                    else if (key < k2) { k2 = key; }
                }
            }
#pragma unroll
            for (int x = 16; x <= 32; x <<= 1) {
                unsigned o1 = __shfl_xor(k1, x);
                unsigned o2 = __shfl_xor(k2, x);
                unsigned n1, n2;
                if (k1 < o1) { n1 = k1; n2 = (k2 < o1) ? k2 : o1; }
                else         { n1 = o1; n2 = (o2 < k1) ? o2 : k1; }
                k1 = n1; k2 = n2;
            }
            if (lane < 16) {
                int token = blk * 64 + th * 32 + nt * 16 + lane;
                *reinterpret_cast<uint2*>(top2 + ((size_t)cblk * N_TOK + token) * 2) =
                    make_uint2(k1, k2);
            }
        }
    }
}

// ---------------- kernel 2: fused exact refine + gather + loss partials ----------------
__global__ __launch_bounds__(256)
void refgather_kernel(const float* __restrict__ z, const float* __restrict__ cb,
                      const float* __restrict__ cnorm, const unsigned* __restrict__ top2,
                      float* __restrict__ out, float* __restrict__ partials) {
    __shared__ float zsm[32][261];
    __shared__ float crows[32][257];
    __shared__ int cand[32][16];
    __shared__ int cnt[32];
    __shared__ u64 bestk[32];
    __shared__ int sidx[32];
    __shared__ float red[256];
    __shared__ int maxc;

    const int t = threadIdx.x;
    const int bh = blockIdx.x;  // 0..1023
    const int b = bh >> 5, h = bh & 31;
    const int n0 = b * 1024 + h * 32;
    const int w = t & 31, dg = t >> 5;

    {   // stage z rows (coalesced 128B segments)
        const float* zp = z + ((size_t)b << 18) + h * 32 + w;
#pragma unroll
        for (int i = 0; i < 32; ++i) {
            int d = dg * 32 + i;
            zsm[w][d] = zp[(size_t)d * 1024];
        }
    }
    if (t < 32) cnt[t] = 0;
    if (t == 0) maxc = 0;
    __syncthreads();

    const int tk = t >> 3, l8 = t & 7;
    {   // candidate collection from per-cblk top-2
        uint2 kk = *reinterpret_cast<const uint2*>(
            top2 + ((size_t)l8 * N_TOK + (n0 + tk)) * 2);
        unsigned mn = kk.x;  // k1 <= k2
#pragma unroll
        for (int x = 1; x < 8; x <<= 1) {
            unsigned o = __shfl_xor(mn, x);
            if (o < mn) mn = o;
        }
        float thr = unpackf(mn & 0xFFFFFC00u) + MARGIN;
        float da = unpackf(kk.x & 0xFFFFFC00u);
        if (da <= thr) { int p = atomicAdd(&cnt[tk], 1); cand[tk][p] = (int)(kk.x & 1023u); }
        float db = unpackf(kk.y & 0xFFFFFC00u);
        if (db <= thr) { int p = atomicAdd(&cnt[tk], 1); cand[tk][p] = (int)(kk.y & 1023u); }
    }
    __syncthreads();
    if (t < 32) atomicMax(&maxc, cnt[t]);
    __syncthreads();

    const int mc = maxc;
    u64 best = ~0ull;
    for (int ci = 0; ci < mc; ++ci) {
        if (ci < cnt[tk]) {
            int k = cand[tk][ci];
            const float* crow = cb + (size_t)k * 256;
            float s = 0.f;
#pragma unroll
            for (int j = 0; j < 32; ++j) {
                int d = j * 8 + l8;
                s = fmaf(zsm[tk][d], crow[d], s);
            }
#pragma unroll
            for (int x = 1; x < 8; x <<= 1) s += __shfl_xor(s, x);
            float d2 = cnorm[k] - 2.f * s;
            u64 key = ((u64)packf(d2) << 32) | (unsigned)k;
            if (key < best) best = key;
        }
    }
    if (l8 == 0) bestk[tk] = best;
    __syncthreads();
    if (t < 32) {
        int k = (int)(bestk[t] & 1023ull);
        sidx[t] = k;
        out[OUT_IDX_OFF + n0 + t] = (float)k;
    }
    __syncthreads();
    {   // stage chosen codebook rows (fp32)
        const int r = t & 31, q = t >> 5;
        const float4* src = reinterpret_cast<const float4*>(cb + (size_t)sidx[r] * 256 + q * 32);
#pragma unroll
        for (int j = 0; j < 8; ++j) {
            float4 v = src[j];
            int d = q * 32 + j * 4;
            crows[r][d] = v.x; crows[r][d + 1] = v.y;
            crows[r][d + 2] = v.z; crows[r][d + 3] = v.w;
        }
    }
    __syncthreads();
    float accl = 0.f;
    float* orow = out + ((size_t)b << 18) + h * 32 + w;
#pragma unroll
    for (int i = 0; i < 32; ++i) {
        const int d = dg * 32 + i;
        const float cv = crows[w][d];
        const float zv = zsm[w][d];
        orow[(size_t)d * 1024] = cv;
        const float df = cv - zv;
        accl += df * df;
    }
    red[t] = accl;
    __syncthreads();
    for (int s = 128; s > 0; s >>= 1) {
        if (t < s) red[t] += red[t + s];
        __syncthreads();
    }
    if (t == 0) partials[bh] = red[0];
}

// ---------------- kernel 3: deterministic final loss reduction ----------------
__global__ __launch_bounds__(256) void loss_kernel(const float* __restrict__ partials,
                                                   float* __restrict__ out) {
    __shared__ float red[256];
    const int t = threadIdx.x;
    float s = partials[t] + partials[t + 256] + partials[t + 512] + partials[t + 768];
    red[t] = s;
    __syncthreads();
    for (int st = 128; st > 0; st >>= 1) {
        if (t < st) red[t] += red[t + st];
        __syncthreads();
    }
    if (t == 0) out[OUT_LOSS_OFF] = red[0] * (1.25f / (float)Z_ELEMS);
}

extern "C" void kernel_launch(void* const* d_in, const int* in_sizes, int n_in,
                              void* d_out, int out_size, void* d_ws, size_t ws_size,
                              hipStream_t stream) {
    const float* z = (const float*)d_in[0];   // [32,256,32,32] f32
    const float* cb = (const float*)d_in[1];  // [1024,256] f32
    float* out = (float*)d_out;
    float* cnorm = (float*)((char*)d_ws + WS_CNORM_OFF);
    float* partials = (float*)((char*)d_ws + WS_PART_OFF);
    unsigned char* cbf = (unsigned char*)d_ws + WS_CBF_OFF;
    unsigned* top2 = (unsigned*)((char*)d_ws + WS_TOP2_OFF);

    prep_kernel<<<16, 256, 0, stream>>>(cb, cnorm, cbf);
    mm_kernel<<<512, 512, 0, stream>>>(z, cbf, cnorm, top2);
    refgather_kernel<<<1024, 256, 0, stream>>>(z, cb, cnorm, top2, out, partials);
    loss_kernel<<<1, 256, 0, stream>>>(partials, out);
}